// Round 3
// baseline (235.507 us; speedup 1.0000x reference)
//
#include <hip/hip_runtime.h>
#include <stdint.h>

// out[b,n] = sum_{c,hw} x[b,c,hw]*W_s[n,hw]*W_d[n,c] + W_b[n]
// GEMM: A = x (M=8192, K=3136), B = W_s (N=1024, K=3136), fused c-contraction.
// R13: eliminate the serialized x->bf16 pass (was 173 MB ~27us at HBM
//      roofline). A is now staged INSIDE the gemm: global fp32 -> regs ->
//      f2bf -> swizzled ds_write_b128, double-buffered 2 K-tiles ahead
//      (named reg bufs, static indexing). B (W_s bf16, converted by a tiny
//      4.5us pass) keeps the global_load_lds path. The compiler's reg-dep
//      vmcnt wait at the convert point IS the counted wait: waiting A(T+2)
//      leaves A(T+3)/B(T+3) in flight (no shared-vmcnt drain -- the R8/R9
//      failure mode). Numerics bit-identical to R10/R12 (same f2bf).

#define K_DIM 3136
#define N_DIM 1024
#define C_DIM 256
#define B_DIM 32
#define M_DIM 8192
#define WS_ELEMS (N_DIM * K_DIM)  // 3211264
#define NSTEP 49                  // K-tiles (BK=32) per split-K half

typedef __attribute__((ext_vector_type(8))) short short8v;  // 8 bf16
typedef __attribute__((ext_vector_type(4))) float f32x4;

__device__ __forceinline__ short f2bf(float f) {
  union { float f; unsigned u; } v; v.f = f;
  unsigned r = v.u + 0x7FFFu + ((v.u >> 16) & 1u);
  return (short)(r >> 16);
}

// 16B-per-lane async global->LDS. LDS dest = wave-uniform base + lane*16.
__device__ __forceinline__ void async16(const void* g, void* l) {
  __builtin_amdgcn_global_load_lds(
      (const __attribute__((address_space(1))) unsigned int*)g,
      (__attribute__((address_space(3))) unsigned int*)l, 16, 0, 0);
}

// fp32 -> bf16 for W_s only (x is converted in-gemm now), plus bias into out.
#define WSBLK (WS_ELEMS / 4096)   // 784
__global__ __launch_bounds__(256) void convert_ws_bias(
    const float* __restrict__ Ws, const float* __restrict__ Wb,
    short* __restrict__ dst, float* __restrict__ out) {
  int bid = blockIdx.x;
  if (bid >= WSBLK) {  // bias: 32768 out elems / 256 = 128 blocks
    int i = (bid - WSBLK) * 256 + threadIdx.x;
    out[i] = Wb[i & (N_DIM - 1)];
    return;
  }
  size_t base = (size_t)bid * 4096;
#pragma unroll
  for (int h = 0; h < 2; ++h) {
    size_t i = base + threadIdx.x * 8 + h * 2048;
    f32x4 v0 = __builtin_nontemporal_load((const f32x4*)(Ws + i));
    f32x4 v1 = __builtin_nontemporal_load((const f32x4*)(Ws + i) + 1);
    short8v s;
    s[0] = f2bf(v0.x); s[1] = f2bf(v0.y); s[2] = f2bf(v0.z); s[3] = f2bf(v0.w);
    s[4] = f2bf(v1.x); s[5] = f2bf(v1.y); s[6] = f2bf(v1.z); s[7] = f2bf(v1.w);
    *(short8v*)(dst + i) = s;
  }
}

// ---- pipelined GEMM, A converted in-kernel ----
// LDS slot s (0..3) at byte s*32768: A[256 rows][32 bf16] then B at +16384.
// Row = 64 B = 4 chunks of 16 B; slot-chunk cs holds global chunk
// cs ^ ((row>>1)&3). B: DMA-linear dest + pre-swizzled global source (as
// before). A: reg-staged, the XOR applied on the ds_write address; write
// mapping (1 row/lane, 64 consecutive rows/wave) covers all 8 bank-quads
// per 8 lanes -> conflict-free b128 writes.

#define VMCNT(N) asm volatile("s_waitcnt vmcnt(" #N ")" ::: "memory")
#define LGKM0() asm volatile("s_waitcnt lgkmcnt(0)" ::: "memory")
#define CBAR() asm volatile("" ::: "memory")
#define BARR() { CBAR(); __builtin_amdgcn_s_barrier(); CBAR(); }

// Issue 16 fp32 (one A generation) into 4 named f32x4 regs; pin position.
#define AISSUE(T, R0, R1, R2, R3) {                                           \
    const f32x4* p_ = (const f32x4*)(Axp + (size_t)(T) * 32);                 \
    R0 = p_[0]; R1 = p_[1]; R2 = p_[2]; R3 = p_[3];                           \
    __builtin_amdgcn_sched_barrier(0); }

// Convert one A generation and write into slot (T)&3 (swizzled). The
// compiler's vmcnt wait on R0..R3 here is the counted pipeline wait.
#define ACVT(T, R0, R1, R2, R3) {                                             \
    short8v lo_, hi_;                                                         \
    lo_[0] = f2bf(R0[0]); lo_[1] = f2bf(R0[1]);                               \
    lo_[2] = f2bf(R0[2]); lo_[3] = f2bf(R0[3]);                               \
    lo_[4] = f2bf(R1[0]); lo_[5] = f2bf(R1[1]);                               \
    lo_[6] = f2bf(R1[2]); lo_[7] = f2bf(R1[3]);                               \
    hi_[0] = f2bf(R2[0]); hi_[1] = f2bf(R2[1]);                               \
    hi_[2] = f2bf(R2[2]); hi_[3] = f2bf(R2[3]);                               \
    hi_[4] = f2bf(R3[0]); hi_[5] = f2bf(R3[1]);                               \
    hi_[6] = f2bf(R3[2]); hi_[7] = f2bf(R3[3]);                               \
    char* sb_ = sm + (((T) & 3) << 15);                                       \
    *(short8v*)(sb_ + aw0) = lo_;                                             \
    *(short8v*)(sb_ + aw1) = hi_;                                             \
    CBAR(); }

#define STAGEB(T) { char* d_ = sm + (((T) & 3) << 15) + 16384 + (wv << 10);   \
    const short* g_ = Bg + (size_t)(T) * 32;                                  \
    async16(g_, d_);                                                          \
    async16(g_ + (size_t)128 * K_DIM, d_ + 8192); }

#define MFQ(F, AV)                                                            \
  acc[F][0] = __builtin_amdgcn_mfma_f32_16x16x32_bf16(AV, b0, acc[F][0], 0, 0, 0); \
  acc[F][1] = __builtin_amdgcn_mfma_f32_16x16x32_bf16(AV, b1, acc[F][1], 0, 0, 0); \
  acc[F][2] = __builtin_amdgcn_mfma_f32_16x16x32_bf16(AV, b2, acc[F][2], 0, 0, 0); \
  acc[F][3] = __builtin_amdgcn_mfma_f32_16x16x32_bf16(AV, b3, acc[F][3], 0, 0, 0);

// One K-tile, 2 phases. ph0: issue A(T+3) fp32->regs; ds_read b0..b3 +
// a-frags 0..3; barrier; 16 MFMA. ph1: convert A(T+2)->slot (compiler
// emits the counted vmcnt), issue B-DMA(T+3), ds_read a-frags 4..7;
// barrier; 16 MFMA. ds_writes precede ds_reads in issue order (CBAR), so
// the pre-MFMA lgkm wait publishes them before the phase-end barrier.
#define KTILE(T, ISS, CVT, BDM)                                               \
  {                                                                           \
    char* sl = sm + (((T) & 3) << 15);                                        \
    ISS                                                                       \
    short8v b0 = *(const short8v*)(sl + boff);                                \
    short8v b1 = *(const short8v*)(sl + boff + 1024);                         \
    short8v b2 = *(const short8v*)(sl + boff + 2048);                         \
    short8v b3 = *(const short8v*)(sl + boff + 3072);                         \
    short8v a0 = *(const short8v*)(sl + aoff);                                \
    short8v a1 = *(const short8v*)(sl + aoff + 1024);                         \
    short8v a2 = *(const short8v*)(sl + aoff + 2048);                         \
    short8v a3 = *(const short8v*)(sl + aoff + 3072);                         \
    BARR();                                                                   \
    __builtin_amdgcn_s_setprio(1);                                            \
    MFQ(0, a0) MFQ(1, a1) MFQ(2, a2) MFQ(3, a3)                               \
    __builtin_amdgcn_s_setprio(0);                                            \
    BARR();                                                                   \
    CVT                                                                       \
    BDM                                                                       \
    a0 = *(const short8v*)(sl + aoff + 4096);                                 \
    a1 = *(const short8v*)(sl + aoff + 5120);                                 \
    a2 = *(const short8v*)(sl + aoff + 6144);                                 \
    a3 = *(const short8v*)(sl + aoff + 7168);                                 \
    BARR();                                                                   \
    __builtin_amdgcn_s_setprio(1);                                            \
    MFQ(4, a0) MFQ(5, a1) MFQ(6, a2) MFQ(7, a3)                               \
    __builtin_amdgcn_s_setprio(0);                                            \
    BARR();                                                                   \
  }

__global__ __launch_bounds__(512, 2) void gemm_fused(
    const float* __restrict__ Ax, const short* __restrict__ Bbf,
    const float* __restrict__ Wd, float* __restrict__ out) {
  __shared__ __align__(16) char sm[131072];  // 128 KiB: 4-slot ring

  // xcd = bid&7 pins (nt, z) per XCD: B z-slice (0.8 MB) L2-resident;
  // same-mt blocks adjacent in dispatch -> the 4 nt-readers of an A-tile
  // stream it through L3 near-simultaneously (1x HBM + 3x L3).
  const int bid = blockIdx.x;
  const int xcd = bid & 7;
  const int nt = xcd >> 1;
  const int z = xcd & 1;            // split-K half: 49 + 49 K-tiles
  const int mt = bid >> 3;
  const int kt0 = z * NSTEP;

  const int tid = threadIdx.x;
  const int lane = tid & 63;
  const int wv = tid >> 6;          // 0..7
  const int r = lane & 15;
  const int q = lane >> 4;
  const int wm = wv >> 2, wn = wv & 3;  // 2M x 4N wave grid, per-wave 128x64

  // A reg-staging: thread -> (row r_ = tid&255, half h_ = tid>>8).
  // Global fp32: 16 contiguous = global chunks {2h, 2h+1}; LDS dest chunk
  // c = g ^ s2, s2 = (r_>>1)&3 (matches the read-side swizzle).
  const int r_ = tid & 255;
  const int h_ = tid >> 8;
  const int s2_ = (r_ >> 1) & 3;
  const int aw0 = r_ * 64 + ((2 * h_ + 0) ^ s2_) * 16;
  const int aw1 = r_ * 64 + ((2 * h_ + 1) ^ s2_) * 16;
  const float* Axp = Ax + (size_t)(mt * 256 + r_) * K_DIM + kt0 * 32 + h_ * 16;

  // B staging (DMA): row = wv*16 + (lane>>2), global chunk pre-swizzled.
  const int srow = wv * 16 + (lane >> 2);
  const int sk8 = (lane & 3) ^ ((lane >> 3) & 3);
  const short* Bg = Bbf + (size_t)(nt * 256 + srow) * K_DIM + kt0 * 32 + sk8 * 8;

  // fragment-read byte offsets within a slot; frag fi/j adds fi*1024.
  const int swz = (q ^ ((r >> 1) & 3)) << 4;
  const int aoff = (wm * 128 + r) * 64 + swz;
  const int boff = 16384 + (wn * 64 + r) * 64 + swz;

  f32x4 acc[8][4];
#pragma unroll
  for (int i = 0; i < 8; ++i)
#pragma unroll
    for (int j = 0; j < 4; ++j) acc[i][j] = (f32x4)0.0f;

  f32x4 ra0, ra1, ra2, ra3;  // even A generations
  f32x4 rb0, rb1, rb2, rb3;  // odd A generations

  // prologue: A gens 0,1 -> regs -> slots 0,1; A gen 2 + B 0,1,2 in flight.
  AISSUE(0, ra0, ra1, ra2, ra3)
  AISSUE(1, rb0, rb1, rb2, rb3)
  STAGEB(0) STAGEB(1)
  ACVT(0, ra0, ra1, ra2, ra3)
  ACVT(1, rb0, rb1, rb2, rb3)
  AISSUE(2, ra0, ra1, ra2, ra3)
  STAGEB(2)
  VMCNT(6);   // drain B(0),B(1); keep A(2)+B(2) in flight
  LGKM0();    // publish A slots 0,1
  BARR();

#pragma unroll 1
  for (int u = 0; u < 23; ++u) {
    const int te = 2 * u;
    KTILE(te, AISSUE(te + 3, rb0, rb1, rb2, rb3),
          ACVT(te + 2, ra0, ra1, ra2, ra3), STAGEB(te + 3))
    KTILE(te + 1, AISSUE(te + 4, ra0, ra1, ra2, ra3),
          ACVT(te + 3, rb0, rb1, rb2, rb3), STAGEB(te + 4))
  }
  // tail: t=46 converts gen 48 (ra) + full drain; 47,48 plain compute.
  KTILE(46, , ACVT(48, ra0, ra1, ra2, ra3) VMCNT(0);, )
  KTILE(47, , , )
  KTILE(48, , , )

  // epilogue: out[mt, n] += sum_c acc * W_d[n, c]; A-tile = image mt, c = row.
  // C/D frag layout: col = lane&15 (n), row = q*4 + reg (c).
#pragma unroll
  for (int j = 0; j < 4; ++j) {
    const int n_g = nt * 256 + wn * 64 + 16 * j + r;
    float p = 0.0f;
#pragma unroll
    for (int i = 0; i < 8; ++i) {
      const int c_l = wm * 128 + 16 * i + 4 * q;
      const float4 wd = *(const float4*)(Wd + (size_t)n_g * C_DIM + c_l);
      p += acc[i][j].x * wd.x + acc[i][j].y * wd.y + acc[i][j].z * wd.z +
           acc[i][j].w * wd.w;
    }
    p += __shfl_xor(p, 16, 64);
    p += __shfl_xor(p, 32, 64);
    if (q == 0) atomicAdd(&out[(size_t)mt * N_DIM + n_g], p);
  }
}

extern "C" void kernel_launch(void* const* d_in, const int* in_sizes, int n_in,
                              void* d_out, int out_size, void* d_ws, size_t ws_size,
                              hipStream_t stream) {
  const float* x = (const float*)d_in[0];
  const float* Ws = (const float*)d_in[1];
  const float* Wd = (const float*)d_in[2];
  const float* Wb = (const float*)d_in[3];
  float* out = (float*)d_out;
  short* wsbf = (short*)d_ws;  // [WS_ELEMS] bf16 W_s only

  convert_ws_bias<<<dim3(WSBLK + 128), dim3(256), 0, stream>>>(Ws, Wb, wsbf, out);
  gemm_fused<<<dim3(32 * 4 * 2), dim3(512), 0, stream>>>(x, wsbf, Wd, out);
}

// Round 4
// 217.300 us; speedup vs baseline: 1.0838x; 1.0838x over previous
//
#include <hip/hip_runtime.h>
#include <stdint.h>

// out[b,n] = sum_{c,hw} x[b,c,hw]*W_s[n,hw]*W_d[n,c] + W_b[n]
// GEMM: A = x (M=8192, K=3136), B = W_s (N=1024, K=3136), fused c-contraction.
// R14: two-pass again (R13's in-gemm fp32-A fetch doubled per-tile bytes and
//      stalled: MfmaUtil 18%). New GEMM inner structure attacks the measured
//      serialization common to R10-R12 (LDS-read windows serialized with MFMA
//      windows by the barrier skeleton: 1240 MFMA + 1150 LDS = ~2750cyc/tile):
//      - mfma_f32_32x32x16_bf16 (two K=16 clusters/tile): -17% MFMA-pipe
//        cycles (2495 vs 2075 TF ceiling), balanced 6+6 ds_reads per cluster.
//      - read-ahead: cluster c+1's ds_reads issue BEFORE cluster c's MFMA
//        block; raw s_barrier doesn't drain lgkm, so reads retire under the
//        MFMAs. Frag double-buffer (f/g), ~200 unified regs, 2 waves/SIMD.
//      - ONE barrier/tile at the vmcnt(8) publish point (counted DMA ring,
//        depth 3, unchanged); WAR on slot reuse separated by that barrier.
//      Staging layout/swizzle byte-identical to R12 (verified conflict-free).

#define K_DIM 3136
#define N_DIM 1024
#define C_DIM 256
#define B_DIM 32
#define M_DIM 8192
#define X_ELEMS (M_DIM * K_DIM)   // 25690112
#define WS_ELEMS (N_DIM * K_DIM)  // 3211264
#define NSTEP 49                  // K-tiles (BK=32) per split-K half

typedef __attribute__((ext_vector_type(8))) short short8v;   // 8 bf16
typedef __attribute__((ext_vector_type(4))) float f32x4;
typedef __attribute__((ext_vector_type(16))) float f32x16;

__device__ __forceinline__ short f2bf(float f) {
  union { float f; unsigned u; } v; v.f = f;
  unsigned r = v.u + 0x7FFFu + ((v.u >> 16) & 1u);
  return (short)(r >> 16);
}

// 16B-per-lane async global->LDS. LDS dest = wave-uniform base + lane*16.
__device__ __forceinline__ void async16(const void* g, void* l) {
  __builtin_amdgcn_global_load_lds(
      (const __attribute__((address_space(1))) unsigned int*)g,
      (__attribute__((address_space(3))) unsigned int*)l, 16, 0, 0);
}

// fp32 -> bf16 for x and W_s (16 elems/thread), plus bias into out.
#define XBLK (X_ELEMS / 4096)                 // 6272
#define CVBLK ((X_ELEMS + WS_ELEMS) / 4096)   // 7056
__global__ __launch_bounds__(256) void convert_bf16_bias(
    const float* __restrict__ x, const float* __restrict__ Ws,
    const float* __restrict__ Wb, short* __restrict__ dst,
    float* __restrict__ out) {
  int bid = blockIdx.x;
  if (bid >= CVBLK) {  // bias: 32768 out elems / 256 = 128 blocks
    int i = (bid - CVBLK) * 256 + threadIdx.x;
    out[i] = Wb[i & (N_DIM - 1)];
    return;
  }
  const float* src;
  short* d;
  size_t base;
  if (bid < XBLK) {
    src = x; d = dst; base = (size_t)bid * 4096;
  } else {
    src = Ws; d = dst + X_ELEMS; base = (size_t)(bid - XBLK) * 4096;
  }
#pragma unroll
  for (int h = 0; h < 2; ++h) {
    size_t i = base + threadIdx.x * 8 + h * 2048;
    f32x4 v0 = __builtin_nontemporal_load((const f32x4*)(src + i));
    f32x4 v1 = __builtin_nontemporal_load((const f32x4*)(src + i) + 1);
    short8v s;
    s[0] = f2bf(v0.x); s[1] = f2bf(v0.y); s[2] = f2bf(v0.z); s[3] = f2bf(v0.w);
    s[4] = f2bf(v1.x); s[5] = f2bf(v1.y); s[6] = f2bf(v1.z); s[7] = f2bf(v1.w);
    *(short8v*)(d + i) = s;
  }
}

// ---- overlap-pipelined GEMM ----
// LDS slot s (0..3) at byte s*32768: A[256 rows][32 bf16] then B at +16384.
// Row = 64 B = 4 chunks of 16 B; slot chunk cs at row holds global chunk
// cs ^ ((row>>1)&3). DMA-linear dest + pre-swizzled global source.
// Reads: global chunk g at row -> slot chunk g ^ ((row>>1)&3). 32-row b128
// column reads spread 8 lanes per bank-quad = LDS minimum (conflict-free).

#define VMCNT(N) asm volatile("s_waitcnt vmcnt(" #N ")" ::: "memory")
#define LGKM0() asm volatile("s_waitcnt lgkmcnt(0)" ::: "memory")
#define SB0() __builtin_amdgcn_sched_barrier(0)
#define CBAR() asm volatile("" ::: "memory")
#define BARR() { CBAR(); __builtin_amdgcn_s_barrier(); CBAR(); }

#define STAGE(T) {                                                            \
    char* da_ = sm + (((T) & 3) << 15) + (wv << 10);                          \
    const short* ga_ = Ag + (size_t)(T) * 32;                                 \
    async16(ga_, da_);                                                        \
    async16(ga_ + (size_t)128 * K_DIM, da_ + 8192);                           \
    const short* gb_ = Bg + (size_t)(T) * 32;                                 \
    async16(gb_, da_ + 16384);                                                \
    async16(gb_ + (size_t)128 * K_DIM, da_ + 24576); }

#define M32(A, B, C) __builtin_amdgcn_mfma_f32_32x32x16_bf16(A, B, C, 0, 0, 0)

#define CLUSTF                                                                \
  acc[0][0]=M32(fa0,fb0,acc[0][0]); acc[1][0]=M32(fa1,fb0,acc[1][0]);         \
  acc[2][0]=M32(fa2,fb0,acc[2][0]); acc[3][0]=M32(fa3,fb0,acc[3][0]);         \
  acc[0][1]=M32(fa0,fb1,acc[0][1]); acc[1][1]=M32(fa1,fb1,acc[1][1]);         \
  acc[2][1]=M32(fa2,fb1,acc[2][1]); acc[3][1]=M32(fa3,fb1,acc[3][1]);

#define CLUSTG                                                                \
  acc[0][0]=M32(ga0,gb0,acc[0][0]); acc[1][0]=M32(ga1,gb0,acc[1][0]);         \
  acc[2][0]=M32(ga2,gb0,acc[2][0]); acc[3][0]=M32(ga3,gb0,acc[3][0]);         \
  acc[0][1]=M32(ga0,gb1,acc[0][1]); acc[1][1]=M32(ga1,gb1,acc[1][1]);         \
  acc[2][1]=M32(ga2,gb1,acc[2][1]); acc[3][1]=M32(ga3,gb1,acc[3][1]);

#define RDF(SL) {                                                             \
    fa0 = *(const short8v*)((SL) + aoff);                                     \
    fa1 = *(const short8v*)((SL) + aoff + 2048);                              \
    fa2 = *(const short8v*)((SL) + aoff + 4096);                              \
    fa3 = *(const short8v*)((SL) + aoff + 6144);                              \
    fb0 = *(const short8v*)((SL) + boff);                                     \
    fb1 = *(const short8v*)((SL) + boff + 2048); }

#define RDG(SL) {                                                             \
    ga0 = *(const short8v*)((SL) + aoffx);                                    \
    ga1 = *(const short8v*)((SL) + aoffx + 2048);                             \
    ga2 = *(const short8v*)((SL) + aoffx + 4096);                             \
    ga3 = *(const short8v*)((SL) + aoffx + 6144);                             \
    gb0 = *(const short8v*)((SL) + boffx);                                    \
    gb1 = *(const short8v*)((SL) + boffx + 2048); }

// One K-tile. Entering: f-frags hold cluster0 of T (read during prev ph1);
// slot T published; slots T+1,T+2 in flight. ph0: stage T+3, read cluster1
// of T (drains under CLUSTF), LGKM0 before the publish barrier (WAR safety),
// counted VMCNT. ph1: read cluster0 of T+1 (slot just published; drains
// under CLUSTG).
#define KT(T, DOSTG, VMS)                                                     \
  {                                                                           \
    char* sl = sm + (((T) & 3) << 15);                                        \
    char* sn = sm + ((((T) + 1) & 3) << 15);                                  \
    if (DOSTG) STAGE((T) + 3);                                                \
    RDG(sl);                                                                  \
    SB0();                                                                    \
    __builtin_amdgcn_s_setprio(1);                                            \
    CLUSTF;                                                                   \
    __builtin_amdgcn_s_setprio(0);                                            \
    LGKM0();                                                                  \
    SB0();                                                                    \
    VMS;                                                                      \
    BARR();                                                                   \
    RDF(sn);                                                                  \
    SB0();                                                                    \
    __builtin_amdgcn_s_setprio(1);                                            \
    CLUSTG;                                                                   \
    __builtin_amdgcn_s_setprio(0);                                            \
  }

__global__ __launch_bounds__(512, 2) void gemm_fused(
    const short* __restrict__ Abf, const short* __restrict__ Bbf,
    const float* __restrict__ Wd, float* __restrict__ out) {
  __shared__ __align__(16) char sm[131072];  // 128 KiB: 4-slot ring

  // xcd = bid&7 pins (nt, z) per XCD: B z-slice (0.8 MB) L2-resident; the 4
  // XCDs of a z-half sweep identical A-tiles in lockstep (L3 sharing).
  const int bid = blockIdx.x;
  const int xcd = bid & 7;
  const int nt = xcd >> 1;
  const int z = xcd & 1;            // split-K half: 49 + 49 K-tiles
  const int mt = bid >> 3;
  const int kt0 = z * NSTEP;

  const int tid = threadIdx.x;
  const int lane = tid & 63;
  const int wv = tid >> 6;          // 0..7
  const int l31 = lane & 31;
  const int q2 = lane >> 5;
  const int wm = wv >> 2, wn = wv & 3;  // 2M x 4N wave grid, per-wave 128x64

  // staging: row = wv*16 + (lane>>2) (+128 for 2nd async16), slot chunk
  // cs = lane&3 holds global chunk cs ^ ((row>>1)&3) = cs ^ ((lane>>3)&3).
  const int srow = wv * 16 + (lane >> 2);
  const int sk8 = (lane & 3) ^ ((lane >> 3) & 3);
  const short* Ag = Abf + (size_t)(mt * 256 + srow) * K_DIM + kt0 * 32 + sk8 * 8;
  const short* Bg = Bbf + (size_t)(nt * 256 + srow) * K_DIM + kt0 * 32 + sk8 * 8;

  // fragment reads (32x32x16): A row = wm*128 + i*32 + l31, k-octet = q2;
  // cluster0 global chunk = q2, cluster1 = q2^2 (byte ^32). Swizzle term
  // s = ((row>>1)&3) = ((l31>>1)&3) (block offsets are multiples of 4 rows).
  const int sA = (l31 >> 1) & 3;
  const int aoff = (wm * 128 + l31) * 64 + ((q2 ^ sA) << 4);
  const int boff = 16384 + (wn * 64 + l31) * 64 + ((q2 ^ sA) << 4);
  const int aoffx = aoff ^ 32;
  const int boffx = boff ^ 32;

  f32x16 acc[4][2];
#pragma unroll
  for (int i = 0; i < 4; ++i)
#pragma unroll
    for (int j = 0; j < 2; ++j) acc[i][j] = (f32x16)0.0f;

  short8v fa0, fa1, fa2, fa3, fb0, fb1;
  short8v ga0, ga1, ga2, ga3, gb0, gb1;

  // prologue: stage 0,1,2 (12 loads); wait tile0 (8 in flight); publish;
  // read cluster0 of tile 0.
  STAGE(0) STAGE(1) STAGE(2)
  VMCNT(8);
  BARR();
  RDF(sm);
  SB0();

#pragma unroll 1
  for (int t = 0; t < NSTEP - 3; ++t) KT(t, 1, VMCNT(8));
  KT(NSTEP - 3, 0, VMCNT(4));  // t=46: 47,48 in flight; need 47
  KT(NSTEP - 2, 0, VMCNT(0));  // t=47: need 48 (final drain)
  KT(NSTEP - 1, 0, (void)0);   // t=48 (trailing RDF reads stale slot: unused)

  // epilogue: out[mt, n] += sum_c acc * W_d[n, c]; A-tile = image mt, c = row.
  // 32x32 C/D layout: col = lane&31 (n), row = (reg&3) + 8*(reg>>2) + 4*q2.
#pragma unroll
  for (int j = 0; j < 2; ++j) {
    const int n_g = nt * 256 + wn * 64 + j * 32 + l31;
    float p = 0.0f;
#pragma unroll
    for (int i = 0; i < 4; ++i) {
      const int cb = wm * 128 + i * 32 + 4 * q2;
#pragma unroll
      for (int g = 0; g < 4; ++g) {
        const float4 wd = *(const float4*)(Wd + (size_t)n_g * C_DIM + cb + 8 * g);
        p += acc[i][j][4 * g + 0] * wd.x + acc[i][j][4 * g + 1] * wd.y +
             acc[i][j][4 * g + 2] * wd.z + acc[i][j][4 * g + 3] * wd.w;
      }
    }
    p += __shfl_xor(p, 32, 64);
    if (q2 == 0) atomicAdd(&out[(size_t)mt * N_DIM + n_g], p);
  }
}

extern "C" void kernel_launch(void* const* d_in, const int* in_sizes, int n_in,
                              void* d_out, int out_size, void* d_ws, size_t ws_size,
                              hipStream_t stream) {
  const float* x = (const float*)d_in[0];
  const float* Ws = (const float*)d_in[1];
  const float* Wd = (const float*)d_in[2];
  const float* Wb = (const float*)d_in[3];
  float* out = (float*)d_out;
  short* xbf = (short*)d_ws;  // [X_ELEMS] bf16 x, then [WS_ELEMS] bf16 W_s

  convert_bf16_bias<<<dim3(CVBLK + 128), dim3(256), 0, stream>>>(x, Ws, Wb, xbf, out);
  gemm_fused<<<dim3(32 * 4 * 2), dim3(512), 0, stream>>>(xbf, xbf + X_ELEMS, Wd, out);
}